// Round 7
// baseline (289.677 us; speedup 1.0000x reference)
//
#include <hip/hip_runtime.h>

#define EDGES 1600000
#define NN    100000
#define ZD    64
#define FD    16
#define HID   128
#define BM    32         // edges per tile
#define THREADS 256
#define NBLK  5000       // 5000 blocks x 10 tiles x 32 edges = 1.6M exactly
#define TPB   10
#define DEPTH 3          // z-stage LDS ring depth (stage t+2 at iter t)

typedef __attribute__((ext_vector_type(8)))  short bfrag;   // 8 bf16 = 4 VGPR
typedef __attribute__((ext_vector_type(16))) float f16v;    // 16 f32 acc

__device__ __forceinline__ unsigned short f2bf(float f) {
  unsigned u = __builtin_bit_cast(unsigned, f);
  u += 0x7fffu + ((u >> 16) & 1u);   // RNE
  return (unsigned short)(u >> 16);
}
__device__ __forceinline__ unsigned cvtpk(float lo, float hi) {
  unsigned r;
  asm("v_cvt_pk_bf16_f32 %0, %1, %2" : "=v"(r) : "v"(lo), "v"(hi));
  return r;
}
__device__ __forceinline__ void gload16(const void* g, void* l) {
  __builtin_amdgcn_global_load_lds(
      (const __attribute__((address_space(1))) unsigned int*)g,
      (__attribute__((address_space(3))) unsigned int*)l, 16, 0, 0);
}

__global__ void zconv_kernel(const float* __restrict__ z,
                             unsigned short* __restrict__ z16, int n4) {
  int i = blockIdx.x * blockDim.x + threadIdx.x;
  if (i >= n4) return;
  float4 f = reinterpret_cast<const float4*>(z)[i];
  ushort4 p;
  p.x = f2bf(f.x); p.y = f2bf(f.y); p.z = f2bf(f.z); p.w = f2bf(f.w);
  reinterpret_cast<ushort4*>(z16)[i] = p;
}

__device__ __forceinline__ bfrag load_wf(const float* __restrict__ W1, int k0, int wcol) {
  const float* p = W1 + (size_t)k0 * HID + wcol;
  int4 q = {(int)cvtpk(p[0],       p[HID]),
            (int)cvtpk(p[2 * HID], p[3 * HID]),
            (int)cvtpk(p[4 * HID], p[5 * HID]),
            (int)cvtpk(p[6 * HID], p[7 * HID])};
  return __builtin_bit_cast(bfrag, q);
}

template<bool ZB>
__device__ __forceinline__ bfrag rd_slice(const char* sb, int lane) {
  if (ZB) {
    return *reinterpret_cast<const bfrag*>(sb + lane * 16);
  } else {
    float4 a = *reinterpret_cast<const float4*>(sb + lane * 16);
    float4 b = *reinterpret_cast<const float4*>(sb + 1024 + lane * 16);
    int4 q = {(int)cvtpk(a.x, a.y), (int)cvtpk(a.z, a.w),
              (int)cvtpk(b.x, b.y), (int)cvtpk(b.z, b.w)};
    return __builtin_bit_cast(bfrag, q);
  }
}

// ============================ PRIMARY ============================
template<bool ZB>
__global__ __launch_bounds__(THREADS, 3) void fused_kernel(
    const float* __restrict__ zf, const unsigned short* __restrict__ z16,
    const int* __restrict__ ei, const float* __restrict__ ea,
    const float* __restrict__ W1, const float* __restrict__ b1,
    const float* __restrict__ W2, const float* __restrict__ b2,
    float* __restrict__ out)
{
  constexpr int SLB = ZB ? 1024 : 2048;
  __shared__ __align__(16) char sl[DEPTH][8][SLB];
  __shared__ float sp[2][4][BM];

  const int tid  = threadIdx.x;
  const int lane = tid & 63;
  const int wid  = tid >> 6;
  const int e    = lane & 31;
  const int hi   = lane >> 5;
  const int s0   = wid * 2;
  const int koff = (s0 & 3) * 16;
  const int T0   = blockIdx.x * TPB;
  const int* eiW = ei + (size_t)(wid >> 1) * EDGES;

  const int wcol = wid * 32 + e;
  bfrag Wf0 = load_wf(W1, 0 * 16 + hi * 8, wcol);
  bfrag Wf1 = load_wf(W1, 1 * 16 + hi * 8, wcol);
  bfrag Wf2 = load_wf(W1, 2 * 16 + hi * 8, wcol);
  bfrag Wf3 = load_wf(W1, 3 * 16 + hi * 8, wcol);
  bfrag Wf4 = load_wf(W1, 4 * 16 + hi * 8, wcol);
  bfrag Wf5 = load_wf(W1, 5 * 16 + hi * 8, wcol);
  bfrag Wf6 = load_wf(W1, 6 * 16 + hi * 8, wcol);
  bfrag Wf7 = load_wf(W1, 7 * 16 + hi * 8, wcol);
  bfrag Wf8 = load_wf(W1, 8 * 16 + hi * 8, wcol);

  f16v b1v, w2v;
  #pragma unroll
  for (int rg = 0; rg < 16; ++rg) {
    int rh = (rg & 3) + 8 * (rg >> 2) + 4 * hi;
    b1v[rg] = b1[wid * 32 + rh];
    w2v[rg] = W2[wid * 32 + rh];
  }
  const float bias2 = b2[0];

#define STAGE(slot, node) do {                                               \
    if (ZB) {                                                                \
      const unsigned short* g0_ = z16 + (size_t)(node) * ZD + koff + hi * 8; \
      gload16(g0_,      &sl[slot][s0][0]);                                   \
      gload16(g0_ + 16, &sl[slot][s0 + 1][0]);                               \
    } else {                                                                 \
      const float* g0_ = zf + (size_t)(node) * ZD + koff + hi * 8;           \
      gload16(g0_,      &sl[slot][s0][0]);                                   \
      gload16(g0_ + 4,  &sl[slot][s0][1024]);                                \
      gload16(g0_ + 16, &sl[slot][s0 + 1][0]);                               \
      gload16(g0_ + 20, &sl[slot][s0 + 1][1024]);                            \
    } } while (0)

  {
    int id0 = eiW[(size_t)T0 * BM + e];
    int id1 = eiW[(size_t)(T0 + 1) * BM + e];
    STAGE(0, id0);
    STAGE(1, id1);
  }
  int idC = eiW[(size_t)(T0 + 2) * BM + e];
  const float* ep0 = ea + ((size_t)T0 * BM + e) * FD + hi * 8;
  float4 eA = *reinterpret_cast<const float4*>(ep0);
  float4 eB = *reinterpret_cast<const float4*>(ep0 + 4);

  int rr = 0, rs = 2;
  for (int t = 0; t < TPB; ++t) {
    if constexpr (ZB) asm volatile("s_waitcnt vmcnt(5) lgkmcnt(0)" ::: "memory");
    else              asm volatile("s_waitcnt vmcnt(7) lgkmcnt(0)" ::: "memory");
    __builtin_amdgcn_s_barrier();

    STAGE(rs, idC);

    if (wid == 0 && t > 0 && lane < 32) {
      int pb = (t - 1) & 1;
      float s = sp[pb][0][e] + sp[pb][1][e] + sp[pb][2][e] + sp[pb][3][e] + bias2;
      out[(size_t)(T0 + t - 1) * BM + e] = 1.f / (1.f + __expf(-s));
    }

    const char* sb = &sl[rr][0][0];
    bfrag x0 = rd_slice<ZB>(sb + 0 * SLB, lane);
    bfrag x1 = rd_slice<ZB>(sb + 1 * SLB, lane);
    bfrag x2 = rd_slice<ZB>(sb + 2 * SLB, lane);
    bfrag x3 = rd_slice<ZB>(sb + 3 * SLB, lane);
    bfrag x4 = rd_slice<ZB>(sb + 4 * SLB, lane);
    bfrag x5 = rd_slice<ZB>(sb + 5 * SLB, lane);
    bfrag x6 = rd_slice<ZB>(sb + 6 * SLB, lane);
    bfrag x7 = rd_slice<ZB>(sb + 7 * SLB, lane);
    int4 eq = {(int)cvtpk(eA.x, eA.y), (int)cvtpk(eA.z, eA.w),
               (int)cvtpk(eB.x, eB.y), (int)cvtpk(eB.z, eB.w)};
    bfrag x8 = __builtin_bit_cast(bfrag, eq);

    {
      int tn = t + 3; if (tn > TPB - 1) tn = TPB - 1;
      idC = eiW[(size_t)(T0 + tn) * BM + e];
      int te = t + 1; if (te > TPB - 1) te = TPB - 1;
      const float* ep = ea + ((size_t)(T0 + te) * BM + e) * FD + hi * 8;
      eA = *reinterpret_cast<const float4*>(ep);
      eB = *reinterpret_cast<const float4*>(ep + 4);
    }

    f16v acc = b1v;
    acc = __builtin_amdgcn_mfma_f32_32x32x16_bf16(Wf0, x0, acc, 0, 0, 0);
    acc = __builtin_amdgcn_mfma_f32_32x32x16_bf16(Wf1, x1, acc, 0, 0, 0);
    acc = __builtin_amdgcn_mfma_f32_32x32x16_bf16(Wf2, x2, acc, 0, 0, 0);
    acc = __builtin_amdgcn_mfma_f32_32x32x16_bf16(Wf3, x3, acc, 0, 0, 0);
    acc = __builtin_amdgcn_mfma_f32_32x32x16_bf16(Wf4, x4, acc, 0, 0, 0);
    acc = __builtin_amdgcn_mfma_f32_32x32x16_bf16(Wf5, x5, acc, 0, 0, 0);
    acc = __builtin_amdgcn_mfma_f32_32x32x16_bf16(Wf6, x6, acc, 0, 0, 0);
    acc = __builtin_amdgcn_mfma_f32_32x32x16_bf16(Wf7, x7, acc, 0, 0, 0);
    acc = __builtin_amdgcn_mfma_f32_32x32x16_bf16(Wf8, x8, acc, 0, 0, 0);

    float p = 0.f;
    #pragma unroll
    for (int rg = 0; rg < 16; ++rg)
      p = fmaf(fmaxf(acc[rg], 0.f), w2v[rg], p);
    p += __shfl_xor(p, 32);
    if (lane < 32) sp[t & 1][wid][e] = p;

    rr = (rr == DEPTH - 1) ? 0 : rr + 1;
    rs = (rs == DEPTH - 1) ? 0 : rs + 1;
  }

  asm volatile("s_waitcnt lgkmcnt(0)" ::: "memory");
  __builtin_amdgcn_s_barrier();
  if (wid == 0 && lane < 32) {
    int pb = (TPB - 1) & 1;
    float s = sp[pb][0][e] + sp[pb][1][e] + sp[pb][2][e] + sp[pb][3][e] + bias2;
    out[(size_t)(T0 + TPB - 1) * BM + e] = 1.f / (1.f + __expf(-s));
  }
  asm volatile("s_waitcnt vmcnt(0)" ::: "memory");
#undef STAGE
}

// ==================== ABLATION A: sequential gather ====================
// Identical machinery; ei loads kept (asm-sunk), but STAGE addresses are
// sequential node ids -> isolates random-gather latency. No global stores.
__global__ __launch_bounds__(THREADS, 3) void abl_seq(
    const unsigned short* __restrict__ z16,
    const int* __restrict__ ei, const float* __restrict__ ea,
    const float* __restrict__ W1, const float* __restrict__ b1,
    const float* __restrict__ W2, const float* __restrict__ b2)
{
  __shared__ __align__(16) char sl[DEPTH][8][1024];
  __shared__ float sp[2][4][BM];

  const int tid  = threadIdx.x;
  const int lane = tid & 63;
  const int wid  = tid >> 6;
  const int e    = lane & 31;
  const int hi   = lane >> 5;
  const int s0   = wid * 2;
  const int koff = (s0 & 3) * 16;
  const int T0   = blockIdx.x * TPB;
  const int* eiW = ei + (size_t)(wid >> 1) * EDGES;

  const int wcol = wid * 32 + e;
  bfrag Wf0 = load_wf(W1, 0 * 16 + hi * 8, wcol);
  bfrag Wf1 = load_wf(W1, 1 * 16 + hi * 8, wcol);
  bfrag Wf2 = load_wf(W1, 2 * 16 + hi * 8, wcol);
  bfrag Wf3 = load_wf(W1, 3 * 16 + hi * 8, wcol);
  bfrag Wf4 = load_wf(W1, 4 * 16 + hi * 8, wcol);
  bfrag Wf5 = load_wf(W1, 5 * 16 + hi * 8, wcol);
  bfrag Wf6 = load_wf(W1, 6 * 16 + hi * 8, wcol);
  bfrag Wf7 = load_wf(W1, 7 * 16 + hi * 8, wcol);
  bfrag Wf8 = load_wf(W1, 8 * 16 + hi * 8, wcol);

  f16v b1v, w2v;
  #pragma unroll
  for (int rg = 0; rg < 16; ++rg) {
    int rh = (rg & 3) + 8 * (rg >> 2) + 4 * hi;
    b1v[rg] = b1[wid * 32 + rh];
    w2v[rg] = W2[wid * 32 + rh];
  }
  const float bias2 = b2[0];

#define SEQID(tt) (int)(((unsigned)(T0 + (tt)) * BM + (unsigned)e) % (unsigned)NN)
#define STAGE(slot, node) do {                                               \
    const unsigned short* g0_ = z16 + (size_t)(node) * ZD + koff + hi * 8;   \
    gload16(g0_,      &sl[slot][s0][0]);                                     \
    gload16(g0_ + 16, &sl[slot][s0 + 1][0]);                                 \
  } while (0)

  {
    int d0 = eiW[(size_t)T0 * BM + e];
    int d1 = eiW[(size_t)(T0 + 1) * BM + e];
    asm volatile("" :: "v"(d0), "v"(d1));
    STAGE(0, SEQID(0));
    STAGE(1, SEQID(1));
  }
  int idC = eiW[(size_t)(T0 + 2) * BM + e];   // dead real load, carried like primary
  const float* ep0 = ea + ((size_t)T0 * BM + e) * FD + hi * 8;
  float4 eA = *reinterpret_cast<const float4*>(ep0);
  float4 eB = *reinterpret_cast<const float4*>(ep0 + 4);

  int rr = 0, rs = 2;
  for (int t = 0; t < TPB; ++t) {
    asm volatile("s_waitcnt vmcnt(5) lgkmcnt(0)" ::: "memory");
    __builtin_amdgcn_s_barrier();

    asm volatile("" :: "v"(idC));          // consume dead id at same point primary uses it
    int tc = t + 2; if (tc > TPB - 1) tc = TPB - 1;
    STAGE(rs, SEQID(tc));

    float outv = 0.f;
    if (wid == 0 && t > 0 && lane < 32) {
      int pb = (t - 1) & 1;
      float s = sp[pb][0][e] + sp[pb][1][e] + sp[pb][2][e] + sp[pb][3][e] + bias2;
      outv = 1.f / (1.f + __expf(-s));
    }
    asm volatile("" :: "v"(outv));

    const char* sb = &sl[rr][0][0];
    bfrag x0 = rd_slice<true>(sb + 0 * 1024, lane);
    bfrag x1 = rd_slice<true>(sb + 1 * 1024, lane);
    bfrag x2 = rd_slice<true>(sb + 2 * 1024, lane);
    bfrag x3 = rd_slice<true>(sb + 3 * 1024, lane);
    bfrag x4 = rd_slice<true>(sb + 4 * 1024, lane);
    bfrag x5 = rd_slice<true>(sb + 5 * 1024, lane);
    bfrag x6 = rd_slice<true>(sb + 6 * 1024, lane);
    bfrag x7 = rd_slice<true>(sb + 7 * 1024, lane);
    int4 eq = {(int)cvtpk(eA.x, eA.y), (int)cvtpk(eA.z, eA.w),
               (int)cvtpk(eB.x, eB.y), (int)cvtpk(eB.z, eB.w)};
    bfrag x8 = __builtin_bit_cast(bfrag, eq);

    {
      int tn = t + 3; if (tn > TPB - 1) tn = TPB - 1;
      idC = eiW[(size_t)(T0 + tn) * BM + e];
      int te = t + 1; if (te > TPB - 1) te = TPB - 1;
      const float* ep = ea + ((size_t)(T0 + te) * BM + e) * FD + hi * 8;
      eA = *reinterpret_cast<const float4*>(ep);
      eB = *reinterpret_cast<const float4*>(ep + 4);
    }

    f16v acc = b1v;
    acc = __builtin_amdgcn_mfma_f32_32x32x16_bf16(Wf0, x0, acc, 0, 0, 0);
    acc = __builtin_amdgcn_mfma_f32_32x32x16_bf16(Wf1, x1, acc, 0, 0, 0);
    acc = __builtin_amdgcn_mfma_f32_32x32x16_bf16(Wf2, x2, acc, 0, 0, 0);
    acc = __builtin_amdgcn_mfma_f32_32x32x16_bf16(Wf3, x3, acc, 0, 0, 0);
    acc = __builtin_amdgcn_mfma_f32_32x32x16_bf16(Wf4, x4, acc, 0, 0, 0);
    acc = __builtin_amdgcn_mfma_f32_32x32x16_bf16(Wf5, x5, acc, 0, 0, 0);
    acc = __builtin_amdgcn_mfma_f32_32x32x16_bf16(Wf6, x6, acc, 0, 0, 0);
    acc = __builtin_amdgcn_mfma_f32_32x32x16_bf16(Wf7, x7, acc, 0, 0, 0);
    acc = __builtin_amdgcn_mfma_f32_32x32x16_bf16(Wf8, x8, acc, 0, 0, 0);

    float p = 0.f;
    #pragma unroll
    for (int rg = 0; rg < 16; ++rg)
      p = fmaf(fmaxf(acc[rg], 0.f), w2v[rg], p);
    p += __shfl_xor(p, 32);
    if (lane < 32) sp[t & 1][wid][e] = p;

    rr = (rr == DEPTH - 1) ? 0 : rr + 1;
    rs = (rs == DEPTH - 1) ? 0 : rs + 1;
  }

  asm volatile("s_waitcnt lgkmcnt(0)" ::: "memory");
  __builtin_amdgcn_s_barrier();
  if (wid == 0 && lane < 32) {
    int pb = (TPB - 1) & 1;
    float s = sp[pb][0][e] + sp[pb][1][e] + sp[pb][2][e] + sp[pb][3][e] + bias2;
    float outv = 1.f / (1.f + __expf(-s));
    asm volatile("" :: "v"(outv));
  }
  asm volatile("s_waitcnt vmcnt(0)" ::: "memory");
#undef STAGE
#undef SEQID
}

// ==================== ABLATION B: no z-staging at all ====================
// x0..x7 cloned from the loop-variant ea fragment (un-hoistable, un-DCE-able);
// ei loads kept+sunk; LDS footprint kept via dummy. Measures compute+barrier+ea floor.
__global__ __launch_bounds__(THREADS, 3) void abl_nostage(
    const unsigned short* __restrict__ z16,
    const int* __restrict__ ei, const float* __restrict__ ea,
    const float* __restrict__ W1, const float* __restrict__ b1,
    const float* __restrict__ W2, const float* __restrict__ b2)
{
  __shared__ __align__(16) char dummy[DEPTH * 8 * 1024];
  __shared__ float sp[2][4][BM];

  const int tid  = threadIdx.x;
  const int lane = tid & 63;
  const int wid  = tid >> 6;
  const int e    = lane & 31;
  const int hi   = lane >> 5;
  const int T0   = blockIdx.x * TPB;
  const int* eiW = ei + (size_t)(wid >> 1) * EDGES;

  dummy[tid] = (char)tid;   // keep LDS allocated

  const int wcol = wid * 32 + e;
  bfrag Wf0 = load_wf(W1, 0 * 16 + hi * 8, wcol);
  bfrag Wf1 = load_wf(W1, 1 * 16 + hi * 8, wcol);
  bfrag Wf2 = load_wf(W1, 2 * 16 + hi * 8, wcol);
  bfrag Wf3 = load_wf(W1, 3 * 16 + hi * 8, wcol);
  bfrag Wf4 = load_wf(W1, 4 * 16 + hi * 8, wcol);
  bfrag Wf5 = load_wf(W1, 5 * 16 + hi * 8, wcol);
  bfrag Wf6 = load_wf(W1, 6 * 16 + hi * 8, wcol);
  bfrag Wf7 = load_wf(W1, 7 * 16 + hi * 8, wcol);
  bfrag Wf8 = load_wf(W1, 8 * 16 + hi * 8, wcol);

  f16v b1v, w2v;
  #pragma unroll
  for (int rg = 0; rg < 16; ++rg) {
    int rh = (rg & 3) + 8 * (rg >> 2) + 4 * hi;
    b1v[rg] = b1[wid * 32 + rh];
    w2v[rg] = W2[wid * 32 + rh];
  }
  const float bias2 = b2[0];

  int idC = eiW[(size_t)(T0 + 2) * BM + e];
  const float* ep0 = ea + ((size_t)T0 * BM + e) * FD + hi * 8;
  float4 eA = *reinterpret_cast<const float4*>(ep0);
  float4 eB = *reinterpret_cast<const float4*>(ep0 + 4);

  for (int t = 0; t < TPB; ++t) {
    asm volatile("s_waitcnt lgkmcnt(0)" ::: "memory");
    __builtin_amdgcn_s_barrier();

    asm volatile("" :: "v"(idC));

    float outv = 0.f;
    if (wid == 0 && t > 0 && lane < 32) {
      int pb = (t - 1) & 1;
      float s = sp[pb][0][e] + sp[pb][1][e] + sp[pb][2][e] + sp[pb][3][e] + bias2;
      outv = 1.f / (1.f + __expf(-s));
    }
    asm volatile("" :: "v"(outv));

    int4 eq = {(int)cvtpk(eA.x, eA.y), (int)cvtpk(eA.z, eA.w),
               (int)cvtpk(eB.x, eB.y), (int)cvtpk(eB.z, eB.w)};
    bfrag x8 = __builtin_bit_cast(bfrag, eq);

    {
      int tn = t + 3; if (tn > TPB - 1) tn = TPB - 1;
      idC = eiW[(size_t)(T0 + tn) * BM + e];
      int te = t + 1; if (te > TPB - 1) te = TPB - 1;
      const float* ep = ea + ((size_t)(T0 + te) * BM + e) * FD + hi * 8;
      eA = *reinterpret_cast<const float4*>(ep);
      eB = *reinterpret_cast<const float4*>(ep + 4);
    }

    f16v acc = b1v;
    acc = __builtin_amdgcn_mfma_f32_32x32x16_bf16(Wf0, x8, acc, 0, 0, 0);
    acc = __builtin_amdgcn_mfma_f32_32x32x16_bf16(Wf1, x8, acc, 0, 0, 0);
    acc = __builtin_amdgcn_mfma_f32_32x32x16_bf16(Wf2, x8, acc, 0, 0, 0);
    acc = __builtin_amdgcn_mfma_f32_32x32x16_bf16(Wf3, x8, acc, 0, 0, 0);
    acc = __builtin_amdgcn_mfma_f32_32x32x16_bf16(Wf4, x8, acc, 0, 0, 0);
    acc = __builtin_amdgcn_mfma_f32_32x32x16_bf16(Wf5, x8, acc, 0, 0, 0);
    acc = __builtin_amdgcn_mfma_f32_32x32x16_bf16(Wf6, x8, acc, 0, 0, 0);
    acc = __builtin_amdgcn_mfma_f32_32x32x16_bf16(Wf7, x8, acc, 0, 0, 0);
    acc = __builtin_amdgcn_mfma_f32_32x32x16_bf16(Wf8, x8, acc, 0, 0, 0);

    float p = 0.f;
    #pragma unroll
    for (int rg = 0; rg < 16; ++rg)
      p = fmaf(fmaxf(acc[rg], 0.f), w2v[rg], p);
    p += __shfl_xor(p, 32);
    if (lane < 32) sp[t & 1][wid][e] = p;
  }

  asm volatile("s_waitcnt lgkmcnt(0)" ::: "memory");
  __builtin_amdgcn_s_barrier();
  if (wid == 0 && lane < 32) {
    int pb = (TPB - 1) & 1;
    float s = sp[pb][0][e] + sp[pb][1][e] + sp[pb][2][e] + sp[pb][3][e] + bias2;
    float outv = 1.f / (1.f + __expf(-s));
    asm volatile("" :: "v"(outv));
  }
}

extern "C" void kernel_launch(void* const* d_in, const int* in_sizes, int n_in,
                              void* d_out, int out_size, void* d_ws, size_t ws_size,
                              hipStream_t stream) {
  const float* z  = (const float*)d_in[0];
  const int*   ei = (const int*)d_in[1];
  const float* ea = (const float*)d_in[2];
  const float* W1 = (const float*)d_in[3];
  const float* b1 = (const float*)d_in[4];
  const float* W2 = (const float*)d_in[5];
  const float* b2 = (const float*)d_in[6];
  float* out = (float*)d_out;

  const size_t z16_bytes = (size_t)NN * ZD * sizeof(unsigned short);
  if (ws_size >= z16_bytes) {
    unsigned short* z16 = (unsigned short*)d_ws;
    const int n4 = NN * ZD / 4;
    zconv_kernel<<<(n4 + 255) / 256, 256, 0, stream>>>(z, z16, n4);
    fused_kernel<true><<<NBLK, THREADS, 0, stream>>>(z, z16, ei, ea, W1, b1, W2, b2, out);
    abl_seq<<<NBLK, THREADS, 0, stream>>>(z16, ei, ea, W1, b1, W2, b2);
    abl_nostage<<<NBLK, THREADS, 0, stream>>>(z16, ei, ea, W1, b1, W2, b2);
  } else {
    fused_kernel<false><<<NBLK, THREADS, 0, stream>>>(z, nullptr, ei, ea, W1, b1, W2, b2, out);
  }
}

// Round 8
// 213.945 us; speedup vs baseline: 1.3540x; 1.3540x over previous
//
#include <hip/hip_runtime.h>

#define EDGES 1600000
#define NN    100000
#define ZD    64
#define FD    16
#define HID   128
#define BM    64         // edges per tile (2 groups of 32)
#define THREADS 256
#define NBLK  2500       // 2500 x 10 x 64 = 1.6M exactly
#define TPB   10

typedef __attribute__((ext_vector_type(8)))  short bfrag;   // 8 bf16 = 4 VGPR
typedef __attribute__((ext_vector_type(16))) float f16v;    // 16 f32 acc

__device__ __forceinline__ unsigned short f2bf(float f) {
  unsigned u = __builtin_bit_cast(unsigned, f);
  u += 0x7fffu + ((u >> 16) & 1u);   // RNE
  return (unsigned short)(u >> 16);
}
__device__ __forceinline__ unsigned cvtpk(float lo, float hi) {
  unsigned r;
  asm("v_cvt_pk_bf16_f32 %0, %1, %2" : "=v"(r) : "v"(lo), "v"(hi));
  return r;
}
__device__ __forceinline__ void gload16(const void* g, void* l) {
  __builtin_amdgcn_global_load_lds(
      (const __attribute__((address_space(1))) unsigned int*)g,
      (__attribute__((address_space(3))) unsigned int*)l, 16, 0, 0);
}

__global__ void zconv_kernel(const float* __restrict__ z,
                             unsigned short* __restrict__ z16, int n4) {
  int i = blockIdx.x * blockDim.x + threadIdx.x;
  if (i >= n4) return;
  float4 f = reinterpret_cast<const float4*>(z)[i];
  ushort4 p;
  p.x = f2bf(f.x); p.y = f2bf(f.y); p.z = f2bf(f.z); p.w = f2bf(f.w);
  reinterpret_cast<ushort4*>(z16)[i] = p;
}

__device__ __forceinline__ bfrag load_wf(const float* __restrict__ W1, int k0, int wcol) {
  const float* p = W1 + (size_t)k0 * HID + wcol;
  int4 q = {(int)cvtpk(p[0],       p[HID]),
            (int)cvtpk(p[2 * HID], p[3 * HID]),
            (int)cvtpk(p[4 * HID], p[5 * HID]),
            (int)cvtpk(p[6 * HID], p[7 * HID])};
  return __builtin_bit_cast(bfrag, q);
}

template<bool ZB>
__device__ __forceinline__ bfrag rd_slice(const char* sb, int lane) {
  if (ZB) {
    return *reinterpret_cast<const bfrag*>(sb + lane * 16);
  } else {
    float4 a = *reinterpret_cast<const float4*>(sb + lane * 16);
    float4 b = *reinterpret_cast<const float4*>(sb + 1024 + lane * 16);
    int4 q = {(int)cvtpk(a.x, a.y), (int)cvtpk(a.z, a.w),
              (int)cvtpk(b.x, b.y), (int)cvtpk(b.z, b.w)};
    return __builtin_bit_cast(bfrag, q);
  }
}

// ============================ PRIMARY (BM=64) ============================
template<bool ZB>
__global__ __launch_bounds__(THREADS, 2) void fused_kernel(
    const float* __restrict__ zf, const unsigned short* __restrict__ z16,
    const int* __restrict__ ei, const float* __restrict__ ea,
    const float* __restrict__ W1, const float* __restrict__ b1,
    const float* __restrict__ W2, const float* __restrict__ b2,
    float* __restrict__ out)
{
  constexpr int SLB = ZB ? 1024 : 2048;            // bytes per 32-edge k-slice
  __shared__ __align__(16) char sl[2][2][8][SLB];  // [buf][group][slice]
  __shared__ float sp[2][4][BM];                   // cross-wave partials

  const int tid  = threadIdx.x;
  const int lane = tid & 63;
  const int wid  = tid >> 6;
  const int e    = lane & 31;
  const int hi   = lane >> 5;
  const int s0   = wid * 2;          // this wave stages slices s0,s0+1 per group
  const int koff = (s0 & 3) * 16;    // k-offset (elems) within node row
  const int T0   = blockIdx.x * TPB;
  const int* eiW = ei + (size_t)(wid >> 1) * EDGES;  // waves 0,1: src; 2,3: dst

  const int wcol = wid * 32 + e;     // MFMA A row = hidden index
  bfrag Wf0 = load_wf(W1, 0 * 16 + hi * 8, wcol);
  bfrag Wf1 = load_wf(W1, 1 * 16 + hi * 8, wcol);
  bfrag Wf2 = load_wf(W1, 2 * 16 + hi * 8, wcol);
  bfrag Wf3 = load_wf(W1, 3 * 16 + hi * 8, wcol);
  bfrag Wf4 = load_wf(W1, 4 * 16 + hi * 8, wcol);
  bfrag Wf5 = load_wf(W1, 5 * 16 + hi * 8, wcol);
  bfrag Wf6 = load_wf(W1, 6 * 16 + hi * 8, wcol);
  bfrag Wf7 = load_wf(W1, 7 * 16 + hi * 8, wcol);
  bfrag Wf8 = load_wf(W1, 8 * 16 + hi * 8, wcol);

  f16v b1v, w2v;
  #pragma unroll
  for (int rg = 0; rg < 16; ++rg) {
    int rh = (rg & 3) + 8 * (rg >> 2) + 4 * hi;
    b1v[rg] = b1[wid * 32 + rh];
    w2v[rg] = W2[wid * 32 + rh];
  }
  const float bias2 = b2[0];

#define STAGE(slot, n0, n1) do {                                               \
    if (ZB) {                                                                  \
      const unsigned short* ga_ = z16 + (size_t)(n0) * ZD + koff + hi * 8;     \
      gload16(ga_,      &sl[slot][0][s0][0]);                                  \
      gload16(ga_ + 16, &sl[slot][0][s0 + 1][0]);                              \
      const unsigned short* gb_ = z16 + (size_t)(n1) * ZD + koff + hi * 8;     \
      gload16(gb_,      &sl[slot][1][s0][0]);                                  \
      gload16(gb_ + 16, &sl[slot][1][s0 + 1][0]);                              \
    } else {                                                                   \
      const float* ga_ = zf + (size_t)(n0) * ZD + koff + hi * 8;               \
      gload16(ga_,      &sl[slot][0][s0][0]);                                  \
      gload16(ga_ + 4,  &sl[slot][0][s0][1024]);                               \
      gload16(ga_ + 16, &sl[slot][0][s0 + 1][0]);                              \
      gload16(ga_ + 20, &sl[slot][0][s0 + 1][1024]);                           \
      const float* gb_ = zf + (size_t)(n1) * ZD + koff + hi * 8;               \
      gload16(gb_,      &sl[slot][1][s0][0]);                                  \
      gload16(gb_ + 4,  &sl[slot][1][s0][1024]);                               \
      gload16(gb_ + 16, &sl[slot][1][s0 + 1][0]);                              \
      gload16(gb_ + 20, &sl[slot][1][s0 + 1][1024]);                           \
    } } while (0)

  // ---- prologue: stage tile 0; load ids(tile1), ea(tile0) ----
  {
    int ia0 = eiW[(size_t)T0 * BM + e];
    int ia1 = eiW[(size_t)T0 * BM + 32 + e];
    STAGE(0, ia0, ia1);
  }
  int ib0 = eiW[(size_t)(T0 + 1) * BM + e];
  int ib1 = eiW[(size_t)(T0 + 1) * BM + 32 + e];
  const float* ep0 = ea + ((size_t)T0 * BM + e) * FD + hi * 8;
  const float* ep1 = ea + ((size_t)T0 * BM + 32 + e) * FD + hi * 8;
  float4 eA0 = *reinterpret_cast<const float4*>(ep0);
  float4 eB0 = *reinterpret_cast<const float4*>(ep0 + 4);
  float4 eA1 = *reinterpret_cast<const float4*>(ep1);
  float4 eB1 = *reinterpret_cast<const float4*>(ep1 + 4);

  for (int t = 0; t < TPB; ++t) {
    const int cur = t & 1, nxt = cur ^ 1;

    // counted wait: per iter a wave issues [stage4, (store), id2, ea4];
    // 6 ops younger than the stage of tile t => vmcnt(6) drains exactly it.
    asm volatile("s_waitcnt vmcnt(6) lgkmcnt(0)" ::: "memory");
    __builtin_amdgcn_s_barrier();

    // stage tile t+1 into buf nxt (ids preloaded last iter; clamped at tail)
    STAGE(nxt, ib0, ib1);
    __builtin_amdgcn_sched_barrier(0);   // pin stage-first vmem order

    // epilogue of tile t-1: all 64 lanes of wave 0, one coalesced store
    if (wid == 0 && t > 0) {
      int pb = (t - 1) & 1;
      float s = sp[pb][0][lane] + sp[pb][1][lane] + sp[pb][2][lane] +
                sp[pb][3][lane] + bias2;
      out[(size_t)(T0 + t - 1) * BM + lane] = 1.f / (1.f + __expf(-s));
    }

    // prefetch ids (tile t+2) and ea (tile t+1)
    int tn = t + 2; if (tn > TPB - 1) tn = TPB - 1;
    int in0 = eiW[(size_t)(T0 + tn) * BM + e];
    int in1 = eiW[(size_t)(T0 + tn) * BM + 32 + e];
    int te = t + 1; if (te > TPB - 1) te = TPB - 1;
    const float* fp0 = ea + ((size_t)(T0 + te) * BM + e) * FD + hi * 8;
    const float* fp1 = ea + ((size_t)(T0 + te) * BM + 32 + e) * FD + hi * 8;
    float4 nA0 = *reinterpret_cast<const float4*>(fp0);
    float4 nB0 = *reinterpret_cast<const float4*>(fp0 + 4);
    float4 nA1 = *reinterpret_cast<const float4*>(fp1);
    float4 nB1 = *reinterpret_cast<const float4*>(fp1 + 4);

    // ---- group 0 ----
    {
      const char* sb = &sl[cur][0][0][0];
      bfrag x0 = rd_slice<ZB>(sb + 0 * SLB, lane);
      bfrag x1 = rd_slice<ZB>(sb + 1 * SLB, lane);
      bfrag x2 = rd_slice<ZB>(sb + 2 * SLB, lane);
      bfrag x3 = rd_slice<ZB>(sb + 3 * SLB, lane);
      bfrag x4 = rd_slice<ZB>(sb + 4 * SLB, lane);
      bfrag x5 = rd_slice<ZB>(sb + 5 * SLB, lane);
      bfrag x6 = rd_slice<ZB>(sb + 6 * SLB, lane);
      bfrag x7 = rd_slice<ZB>(sb + 7 * SLB, lane);
      int4 eq = {(int)cvtpk(eA0.x, eA0.y), (int)cvtpk(eA0.z, eA0.w),
                 (int)cvtpk(eB0.x, eB0.y), (int)cvtpk(eB0.z, eB0.w)};
      bfrag x8 = __builtin_bit_cast(bfrag, eq);

      f16v acc = b1v;
      acc = __builtin_amdgcn_mfma_f32_32x32x16_bf16(Wf0, x0, acc, 0, 0, 0);
      acc = __builtin_amdgcn_mfma_f32_32x32x16_bf16(Wf1, x1, acc, 0, 0, 0);
      acc = __builtin_amdgcn_mfma_f32_32x32x16_bf16(Wf2, x2, acc, 0, 0, 0);
      acc = __builtin_amdgcn_mfma_f32_32x32x16_bf16(Wf3, x3, acc, 0, 0, 0);
      acc = __builtin_amdgcn_mfma_f32_32x32x16_bf16(Wf4, x4, acc, 0, 0, 0);
      acc = __builtin_amdgcn_mfma_f32_32x32x16_bf16(Wf5, x5, acc, 0, 0, 0);
      acc = __builtin_amdgcn_mfma_f32_32x32x16_bf16(Wf6, x6, acc, 0, 0, 0);
      acc = __builtin_amdgcn_mfma_f32_32x32x16_bf16(Wf7, x7, acc, 0, 0, 0);
      acc = __builtin_amdgcn_mfma_f32_32x32x16_bf16(Wf8, x8, acc, 0, 0, 0);

      float pa = 0.f, pb_ = 0.f;
      #pragma unroll
      for (int rg = 0; rg < 8; ++rg) {
        pa = fmaf(fmaxf(acc[2 * rg], 0.f),     w2v[2 * rg],     pa);
        pb_ = fmaf(fmaxf(acc[2 * rg + 1], 0.f), w2v[2 * rg + 1], pb_);
      }
      float p = pa + pb_;
      p += __shfl_xor(p, 32);
      if (lane < 32) sp[cur][wid][e] = p;
    }
    // ---- group 1 ----
    {
      const char* sb = &sl[cur][1][0][0];
      bfrag x0 = rd_slice<ZB>(sb + 0 * SLB, lane);
      bfrag x1 = rd_slice<ZB>(sb + 1 * SLB, lane);
      bfrag x2 = rd_slice<ZB>(sb + 2 * SLB, lane);
      bfrag x3 = rd_slice<ZB>(sb + 3 * SLB, lane);
      bfrag x4 = rd_slice<ZB>(sb + 4 * SLB, lane);
      bfrag x5 = rd_slice<ZB>(sb + 5 * SLB, lane);
      bfrag x6 = rd_slice<ZB>(sb + 6 * SLB, lane);
      bfrag x7 = rd_slice<ZB>(sb + 7 * SLB, lane);
      int4 eq = {(int)cvtpk(eA1.x, eA1.y), (int)cvtpk(eA1.z, eA1.w),
                 (int)cvtpk(eB1.x, eB1.y), (int)cvtpk(eB1.z, eB1.w)};
      bfrag x8 = __builtin_bit_cast(bfrag, eq);

      f16v acc = b1v;
      acc = __builtin_amdgcn_mfma_f32_32x32x16_bf16(Wf0, x0, acc, 0, 0, 0);
      acc = __builtin_amdgcn_mfma_f32_32x32x16_bf16(Wf1, x1, acc, 0, 0, 0);
      acc = __builtin_amdgcn_mfma_f32_32x32x16_bf16(Wf2, x2, acc, 0, 0, 0);
      acc = __builtin_amdgcn_mfma_f32_32x32x16_bf16(Wf3, x3, acc, 0, 0, 0);
      acc = __builtin_amdgcn_mfma_f32_32x32x16_bf16(Wf4, x4, acc, 0, 0, 0);
      acc = __builtin_amdgcn_mfma_f32_32x32x16_bf16(Wf5, x5, acc, 0, 0, 0);
      acc = __builtin_amdgcn_mfma_f32_32x32x16_bf16(Wf6, x6, acc, 0, 0, 0);
      acc = __builtin_amdgcn_mfma_f32_32x32x16_bf16(Wf7, x7, acc, 0, 0, 0);
      acc = __builtin_amdgcn_mfma_f32_32x32x16_bf16(Wf8, x8, acc, 0, 0, 0);

      float pa = 0.f, pb_ = 0.f;
      #pragma unroll
      for (int rg = 0; rg < 8; ++rg) {
        pa = fmaf(fmaxf(acc[2 * rg], 0.f),     w2v[2 * rg],     pa);
        pb_ = fmaf(fmaxf(acc[2 * rg + 1], 0.f), w2v[2 * rg + 1], pb_);
      }
      float p = pa + pb_;
      p += __shfl_xor(p, 32);
      if (lane < 32) sp[cur][wid][32 + e] = p;
    }

    ib0 = in0; ib1 = in1;
    eA0 = nA0; eB0 = nB0; eA1 = nA1; eB1 = nB1;
  }

  // drain: finish last tile
  asm volatile("s_waitcnt lgkmcnt(0)" ::: "memory");
  __builtin_amdgcn_s_barrier();
  if (wid == 0) {
    int pb = (TPB - 1) & 1;
    float s = sp[pb][0][lane] + sp[pb][1][lane] + sp[pb][2][lane] +
              sp[pb][3][lane] + bias2;
    out[(size_t)(T0 + TPB - 1) * BM + lane] = 1.f / (1.f + __expf(-s));
  }
  asm volatile("s_waitcnt vmcnt(0)" ::: "memory");  // pending LDS-DMA drain
#undef STAGE
}

// ==================== ABLATION: sequential gather (round-7 verbatim) ====================
#define ABM 32
#define ABL_NBLK 5000
#define ABL_DEPTH 3
__global__ __launch_bounds__(THREADS, 3) void abl_seq(
    const unsigned short* __restrict__ z16,
    const int* __restrict__ ei, const float* __restrict__ ea,
    const float* __restrict__ W1, const float* __restrict__ b1,
    const float* __restrict__ W2, const float* __restrict__ b2)
{
  __shared__ __align__(16) char sl[ABL_DEPTH][8][1024];
  __shared__ float sp[2][4][ABM];

  const int tid  = threadIdx.x;
  const int lane = tid & 63;
  const int wid  = tid >> 6;
  const int e    = lane & 31;
  const int hi   = lane >> 5;
  const int s0   = wid * 2;
  const int koff = (s0 & 3) * 16;
  const int T0   = blockIdx.x * TPB;
  const int* eiW = ei + (size_t)(wid >> 1) * EDGES;

  const int wcol = wid * 32 + e;
  bfrag Wf0 = load_wf(W1, 0 * 16 + hi * 8, wcol);
  bfrag Wf1 = load_wf(W1, 1 * 16 + hi * 8, wcol);
  bfrag Wf2 = load_wf(W1, 2 * 16 + hi * 8, wcol);
  bfrag Wf3 = load_wf(W1, 3 * 16 + hi * 8, wcol);
  bfrag Wf4 = load_wf(W1, 4 * 16 + hi * 8, wcol);
  bfrag Wf5 = load_wf(W1, 5 * 16 + hi * 8, wcol);
  bfrag Wf6 = load_wf(W1, 6 * 16 + hi * 8, wcol);
  bfrag Wf7 = load_wf(W1, 7 * 16 + hi * 8, wcol);
  bfrag Wf8 = load_wf(W1, 8 * 16 + hi * 8, wcol);

  f16v b1v, w2v;
  #pragma unroll
  for (int rg = 0; rg < 16; ++rg) {
    int rh = (rg & 3) + 8 * (rg >> 2) + 4 * hi;
    b1v[rg] = b1[wid * 32 + rh];
    w2v[rg] = W2[wid * 32 + rh];
  }
  const float bias2 = b2[0];

#define SEQID(tt) (int)(((unsigned)(T0 + (tt)) * ABM + (unsigned)e) % (unsigned)NN)
#define ASTAGE(slot, node) do {                                              \
    const unsigned short* g0_ = z16 + (size_t)(node) * ZD + koff + hi * 8;   \
    gload16(g0_,      &sl[slot][s0][0]);                                     \
    gload16(g0_ + 16, &sl[slot][s0 + 1][0]);                                 \
  } while (0)

  {
    int d0 = eiW[(size_t)T0 * ABM + e];
    int d1 = eiW[(size_t)(T0 + 1) * ABM + e];
    asm volatile("" :: "v"(d0), "v"(d1));
    ASTAGE(0, SEQID(0));
    ASTAGE(1, SEQID(1));
  }
  int idC = eiW[(size_t)(T0 + 2) * ABM + e];
  const float* ep0 = ea + ((size_t)T0 * ABM + e) * FD + hi * 8;
  float4 eA = *reinterpret_cast<const float4*>(ep0);
  float4 eB = *reinterpret_cast<const float4*>(ep0 + 4);

  int rr = 0, rs = 2;
  for (int t = 0; t < TPB; ++t) {
    asm volatile("s_waitcnt vmcnt(5) lgkmcnt(0)" ::: "memory");
    __builtin_amdgcn_s_barrier();

    asm volatile("" :: "v"(idC));
    int tc = t + 2; if (tc > TPB - 1) tc = TPB - 1;
    ASTAGE(rs, SEQID(tc));

    float outv = 0.f;
    if (wid == 0 && t > 0 && lane < 32) {
      int pb = (t - 1) & 1;
      float s = sp[pb][0][e] + sp[pb][1][e] + sp[pb][2][e] + sp[pb][3][e] + bias2;
      outv = 1.f / (1.f + __expf(-s));
    }
    asm volatile("" :: "v"(outv));

    const char* sb = &sl[rr][0][0];
    bfrag x0 = rd_slice<true>(sb + 0 * 1024, lane);
    bfrag x1 = rd_slice<true>(sb + 1 * 1024, lane);
    bfrag x2 = rd_slice<true>(sb + 2 * 1024, lane);
    bfrag x3 = rd_slice<true>(sb + 3 * 1024, lane);
    bfrag x4 = rd_slice<true>(sb + 4 * 1024, lane);
    bfrag x5 = rd_slice<true>(sb + 5 * 1024, lane);
    bfrag x6 = rd_slice<true>(sb + 6 * 1024, lane);
    bfrag x7 = rd_slice<true>(sb + 7 * 1024, lane);
    int4 eq = {(int)cvtpk(eA.x, eA.y), (int)cvtpk(eA.z, eA.w),
               (int)cvtpk(eB.x, eB.y), (int)cvtpk(eB.z, eB.w)};
    bfrag x8 = __builtin_bit_cast(bfrag, eq);

    {
      int tn = t + 3; if (tn > TPB - 1) tn = TPB - 1;
      idC = eiW[(size_t)(T0 + tn) * ABM + e];
      int te = t + 1; if (te > TPB - 1) te = TPB - 1;
      const float* ep = ea + ((size_t)(T0 + te) * ABM + e) * FD + hi * 8;
      eA = *reinterpret_cast<const float4*>(ep);
      eB = *reinterpret_cast<const float4*>(ep + 4);
    }

    f16v acc = b1v;
    acc = __builtin_amdgcn_mfma_f32_32x32x16_bf16(Wf0, x0, acc, 0, 0, 0);
    acc = __builtin_amdgcn_mfma_f32_32x32x16_bf16(Wf1, x1, acc, 0, 0, 0);
    acc = __builtin_amdgcn_mfma_f32_32x32x16_bf16(Wf2, x2, acc, 0, 0, 0);
    acc = __builtin_amdgcn_mfma_f32_32x32x16_bf16(Wf3, x3, acc, 0, 0, 0);
    acc = __builtin_amdgcn_mfma_f32_32x32x16_bf16(Wf4, x4, acc, 0, 0, 0);
    acc = __builtin_amdgcn_mfma_f32_32x32x16_bf16(Wf5, x5, acc, 0, 0, 0);
    acc = __builtin_amdgcn_mfma_f32_32x32x16_bf16(Wf6, x6, acc, 0, 0, 0);
    acc = __builtin_amdgcn_mfma_f32_32x32x16_bf16(Wf7, x7, acc, 0, 0, 0);
    acc = __builtin_amdgcn_mfma_f32_32x32x16_bf16(Wf8, x8, acc, 0, 0, 0);

    float p = 0.f;
    #pragma unroll
    for (int rg = 0; rg < 16; ++rg)
      p = fmaf(fmaxf(acc[rg], 0.f), w2v[rg], p);
    p += __shfl_xor(p, 32);
    if (lane < 32) sp[t & 1][wid][e] = p;

    rr = (rr == ABL_DEPTH - 1) ? 0 : rr + 1;
    rs = (rs == ABL_DEPTH - 1) ? 0 : rs + 1;
  }

  asm volatile("s_waitcnt lgkmcnt(0)" ::: "memory");
  __builtin_amdgcn_s_barrier();
  if (wid == 0 && lane < 32) {
    int pb = (TPB - 1) & 1;
    float s = sp[pb][0][e] + sp[pb][1][e] + sp[pb][2][e] + sp[pb][3][e] + bias2;
    float outv = 1.f / (1.f + __expf(-s));
    asm volatile("" :: "v"(outv));
  }
  asm volatile("s_waitcnt vmcnt(0)" ::: "memory");
#undef ASTAGE
#undef SEQID
}

extern "C" void kernel_launch(void* const* d_in, const int* in_sizes, int n_in,
                              void* d_out, int out_size, void* d_ws, size_t ws_size,
                              hipStream_t stream) {
  const float* z  = (const float*)d_in[0];
  const int*   ei = (const int*)d_in[1];
  const float* ea = (const float*)d_in[2];
  const float* W1 = (const float*)d_in[3];
  const float* b1 = (const float*)d_in[4];
  const float* W2 = (const float*)d_in[5];
  const float* b2 = (const float*)d_in[6];
  float* out = (float*)d_out;

  const size_t z16_bytes = (size_t)NN * ZD * sizeof(unsigned short);
  if (ws_size >= z16_bytes) {
    unsigned short* z16 = (unsigned short*)d_ws;
    const int n4 = NN * ZD / 4;
    zconv_kernel<<<(n4 + 255) / 256, 256, 0, stream>>>(z, z16, n4);
    fused_kernel<true><<<NBLK, THREADS, 0, stream>>>(z, z16, ei, ea, W1, b1, W2, b2, out);
    abl_seq<<<ABL_NBLK, THREADS, 0, stream>>>(z16, ei, ea, W1, b1, W2, b2);
  } else {
    fused_kernel<false><<<NBLK, THREADS, 0, stream>>>(z, nullptr, ei, ea, W1, b1, W2, b2, out);
  }
}

// Round 9
// 120.873 us; speedup vs baseline: 2.3965x; 1.7700x over previous
//
#include <hip/hip_runtime.h>

#define EDGES 1600000
#define NN    100000
#define ZD    64
#define FD    16
#define HID   128
#define BM    16          // edges per wave-tile
#define KP    160         // K padded (144 -> 160)
#define NBLK  6250        // 6250 blocks x 1 wave x 16 tiles x 16 edges = 1.6M
#define TPW   16

typedef __attribute__((ext_vector_type(8))) short bfrag;   // 8 bf16 = 4 VGPR
typedef __attribute__((ext_vector_type(4))) float f4v;     // 4 f32 acc

__device__ __forceinline__ unsigned short f2bf(float f) {
  unsigned u = __builtin_bit_cast(unsigned, f);
  u += 0x7fffu + ((u >> 16) & 1u);   // RNE
  return (unsigned short)(u >> 16);
}
__device__ __forceinline__ unsigned cvtpk(float lo, float hi) {
  unsigned r;
  asm("v_cvt_pk_bf16_f32 %0, %1, %2" : "=v"(r) : "v"(lo), "v"(hi));
  return r;
}

// z (f32) -> bf16 table in ws
__global__ void zconv_kernel(const float* __restrict__ z,
                             unsigned short* __restrict__ z16, int n4) {
  int i = blockIdx.x * blockDim.x + threadIdx.x;
  if (i >= n4) return;
  float4 f = reinterpret_cast<const float4*>(z)[i];
  ushort4 p;
  p.x = f2bf(f.x); p.y = f2bf(f.y); p.z = f2bf(f.z); p.w = f2bf(f.w);
  reinterpret_cast<ushort4*>(z16)[i] = p;
}

// W1 (f32, [144][128]) -> W1^T bf16 [128][160] (k-padded with zeros) in ws
__global__ void wtconv_kernel(const float* __restrict__ W1,
                              unsigned short* __restrict__ W16T) {
  int i = blockIdx.x * blockDim.x + threadIdx.x;
  if (i >= HID * KP) return;
  int h = i / KP, k = i % KP;
  W16T[i] = (k < 144) ? f2bf(W1[k * HID + h]) : (unsigned short)0;
}

template<bool ZB>
__global__ __launch_bounds__(64, 2) void fused_kernel(
    const float* __restrict__ zf, const unsigned short* __restrict__ z16,
    const unsigned short* __restrict__ W16T,
    const int* __restrict__ ei, const float* __restrict__ ea,
    const float* __restrict__ W1, const float* __restrict__ b1,
    const float* __restrict__ W2, const float* __restrict__ b2,
    float* __restrict__ out)
{
  const int lane = threadIdx.x & 63;
  const int e    = lane & 15;        // edge within tile (= A row = D row-group col)
  const int hi2  = lane >> 4;        // 0..3 (k-slice / D row-quad)
  const int T0   = blockIdx.x * TPW;

  // ---- W1^T fragments, W-stationary in registers (8 blk x 5 ks = 160 VGPR) ----
  // frag[j] = W1T[hid = blk*16+e][k = ks*32 + hi2*8 + j]
  bfrag Wb[8][5];
  if constexpr (ZB) {
    #pragma unroll
    for (int blk = 0; blk < 8; ++blk) {
      const unsigned short* wr = W16T + (size_t)(blk * 16 + e) * KP + hi2 * 8;
      #pragma unroll
      for (int ks = 0; ks < 5; ++ks)
        Wb[blk][ks] = *reinterpret_cast<const bfrag*>(wr + ks * 32);
    }
  } else {
    #pragma unroll
    for (int blk = 0; blk < 8; ++blk) {
      const int wcol = blk * 16 + e;
      #pragma unroll
      for (int ks = 0; ks < 5; ++ks) {
        bfrag f;
        #pragma unroll
        for (int j = 0; j < 8; ++j) {
          int kk = ks * 32 + hi2 * 8 + j;
          if (kk > 143) kk = 143;      // A-side zeroed there; just stay in-bounds
          f[j] = (short)f2bf(W1[kk * HID + wcol]);
        }
        Wb[blk][ks] = f;
      }
    }
  }

  float b1v[8], w2v[8];
  #pragma unroll
  for (int blk = 0; blk < 8; ++blk) {
    b1v[blk] = b1[blk * 16 + e];
    w2v[blk] = W2[blk * 16 + e];
  }
  const float bias2 = b2[0];
  const unsigned eam = (hi2 < 2) ? 0xFFFFFFFFu : 0u;   // k>=144 pad mask
  const int eoff = (hi2 & 1) * 8;

  // gather of one tile's z fragments (per-lane: edge e, k-slice hi2)
#define GZ(x0, x1, x2, x3, si, di) do {                                        \
    if constexpr (ZB) {                                                        \
      const unsigned short* ps_ = z16 + (size_t)(si) * ZD + hi2 * 8;           \
      const unsigned short* pd_ = z16 + (size_t)(di) * ZD + hi2 * 8;           \
      x0 = *reinterpret_cast<const bfrag*>(ps_);                               \
      x1 = *reinterpret_cast<const bfrag*>(ps_ + 32);                          \
      x2 = *reinterpret_cast<const bfrag*>(pd_);                               \
      x3 = *reinterpret_cast<const bfrag*>(pd_ + 32);                          \
    } else {                                                                   \
      const float* ps_ = zf + (size_t)(si) * ZD + hi2 * 8;                     \
      const float* pd_ = zf + (size_t)(di) * ZD + hi2 * 8;                     \
      float4 a_, b_;                                                           \
      a_ = ((const float4*)ps_)[0]; b_ = ((const float4*)ps_)[1];              \
      { int4 q_ = {(int)cvtpk(a_.x,a_.y),(int)cvtpk(a_.z,a_.w),               \
                   (int)cvtpk(b_.x,b_.y),(int)cvtpk(b_.z,b_.w)};              \
        x0 = __builtin_bit_cast(bfrag, q_); }                                  \
      a_ = ((const float4*)(ps_+32))[0]; b_ = ((const float4*)(ps_+32))[1];    \
      { int4 q_ = {(int)cvtpk(a_.x,a_.y),(int)cvtpk(a_.z,a_.w),               \
                   (int)cvtpk(b_.x,b_.y),(int)cvtpk(b_.z,b_.w)};              \
        x1 = __builtin_bit_cast(bfrag, q_); }                                  \
      a_ = ((const float4*)pd_)[0]; b_ = ((const float4*)pd_)[1];              \
      { int4 q_ = {(int)cvtpk(a_.x,a_.y),(int)cvtpk(a_.z,a_.w),               \
                   (int)cvtpk(b_.x,b_.y),(int)cvtpk(b_.z,b_.w)};              \
        x2 = __builtin_bit_cast(bfrag, q_); }                                  \
      a_ = ((const float4*)(pd_+32))[0]; b_ = ((const float4*)(pd_+32))[1];    \
      { int4 q_ = {(int)cvtpk(a_.x,a_.y),(int)cvtpk(a_.z,a_.w),               \
                   (int)cvtpk(b_.x,b_.y),(int)cvtpk(b_.z,b_.w)};              \
        x3 = __builtin_bit_cast(bfrag, q_); }                                  \
    } } while (0)

  // ---- prologue: gather tile 0; ids for tile 1 ----
  int si0 = ei[(size_t)T0 * BM + e];
  int di0 = ei[(size_t)EDGES + (size_t)T0 * BM + e];
  bfrag c0, c1, c2, c3;
  GZ(c0, c1, c2, c3, si0, di0);
  const float* pe0 = ea + ((size_t)T0 * BM + e) * FD + eoff;
  float4 ca = ((const float4*)pe0)[0];
  float4 cb = ((const float4*)pe0)[1];
  int si1 = ei[(size_t)(T0 + 1) * BM + e];
  int di1 = ei[(size_t)EDGES + (size_t)(T0 + 1) * BM + e];

  for (int t = 0; t < TPW; ++t) {
    const int tt = T0 + t;

    // issue next-tile gathers (consumed next iteration -> latency hidden)
    bfrag n0, n1, n2, n3;
    GZ(n0, n1, n2, n3, si1, di1);
    const int te = (t + 1 < TPW) ? tt + 1 : tt;
    const float* pen = ea + ((size_t)te * BM + e) * FD + eoff;
    float4 na = ((const float4*)pen)[0];
    float4 nb = ((const float4*)pen)[1];
    // ids for tile t+2
    const int tf = (t + 2 < TPW) ? tt + 2 : T0 + TPW - 1;
    si1 = ei[(size_t)tf * BM + e];
    di1 = ei[(size_t)EDGES + (size_t)tf * BM + e];

    // build current ea fragment (k 128..159; upper 16 zero-padded)
    int4 q = {(int)(cvtpk(ca.x, ca.y) & eam), (int)(cvtpk(ca.z, ca.w) & eam),
              (int)(cvtpk(cb.x, cb.y) & eam), (int)(cvtpk(cb.z, cb.w) & eam)};
    bfrag c4 = __builtin_bit_cast(bfrag, q);

    // ---- 40 MFMAs: D[row=edge][col=hid], lane holds col=e, rows hi2*4+r ----
    float p0 = 0.f, p1 = 0.f, p2 = 0.f, p3 = 0.f;
    #pragma unroll
    for (int blk = 0; blk < 8; ++blk) {
      f4v acc = {0.f, 0.f, 0.f, 0.f};
      acc = __builtin_amdgcn_mfma_f32_16x16x32_bf16(c0, Wb[blk][0], acc, 0, 0, 0);
      acc = __builtin_amdgcn_mfma_f32_16x16x32_bf16(c1, Wb[blk][1], acc, 0, 0, 0);
      acc = __builtin_amdgcn_mfma_f32_16x16x32_bf16(c2, Wb[blk][2], acc, 0, 0, 0);
      acc = __builtin_amdgcn_mfma_f32_16x16x32_bf16(c3, Wb[blk][3], acc, 0, 0, 0);
      acc = __builtin_amdgcn_mfma_f32_16x16x32_bf16(c4, Wb[blk][4], acc, 0, 0, 0);
      p0 = fmaf(fmaxf(acc[0] + b1v[blk], 0.f), w2v[blk], p0);
      p1 = fmaf(fmaxf(acc[1] + b1v[blk], 0.f), w2v[blk], p1);
      p2 = fmaf(fmaxf(acc[2] + b1v[blk], 0.f), w2v[blk], p2);
      p3 = fmaf(fmaxf(acc[3] + b1v[blk], 0.f), w2v[blk], p3);
    }

    // reduce over the 16 hid-lanes of this group
    p0 += __shfl_xor(p0, 1); p0 += __shfl_xor(p0, 2);
    p0 += __shfl_xor(p0, 4); p0 += __shfl_xor(p0, 8);
    p1 += __shfl_xor(p1, 1); p1 += __shfl_xor(p1, 2);
    p1 += __shfl_xor(p1, 4); p1 += __shfl_xor(p1, 8);
    p2 += __shfl_xor(p2, 1); p2 += __shfl_xor(p2, 2);
    p2 += __shfl_xor(p2, 4); p2 += __shfl_xor(p2, 8);
    p3 += __shfl_xor(p3, 1); p3 += __shfl_xor(p3, 2);
    p3 += __shfl_xor(p3, 4); p3 += __shfl_xor(p3, 8);

    // lanes (e<4) store rows hi2*4 + (lane&3): 16 consecutive floats
    float v01 = (lane & 1) ? p1 : p0;
    float v23 = (lane & 1) ? p3 : p2;
    float v   = (lane & 2) ? v23 : v01;
    if (e < 4)
      out[(size_t)tt * BM + hi2 * 4 + (lane & 3)] =
          1.f / (1.f + __expf(-(v + bias2)));

    // rotate
    c0 = n0; c1 = n1; c2 = n2; c3 = n3; ca = na; cb = nb;
  }
#undef GZ
}

extern "C" void kernel_launch(void* const* d_in, const int* in_sizes, int n_in,
                              void* d_out, int out_size, void* d_ws, size_t ws_size,
                              hipStream_t stream) {
  const float* z  = (const float*)d_in[0];
  const int*   ei = (const int*)d_in[1];
  const float* ea = (const float*)d_in[2];
  const float* W1 = (const float*)d_in[3];
  const float* b1 = (const float*)d_in[4];
  const float* W2 = (const float*)d_in[5];
  const float* b2 = (const float*)d_in[6];
  float* out = (float*)d_out;

  const size_t z16_bytes = (size_t)NN * ZD * sizeof(unsigned short);
  const size_t wt_bytes  = (size_t)HID * KP * sizeof(unsigned short);
  if (ws_size >= z16_bytes + wt_bytes) {
    unsigned short* z16  = (unsigned short*)d_ws;
    unsigned short* W16T = z16 + (size_t)NN * ZD;
    const int n4 = NN * ZD / 4;
    zconv_kernel<<<(n4 + 255) / 256, 256, 0, stream>>>(z, z16, n4);
    wtconv_kernel<<<(HID * KP + 255) / 256, 256, 0, stream>>>(W1, W16T);
    fused_kernel<true><<<NBLK, 64, 0, stream>>>(
        z, z16, W16T, ei, ea, W1, b1, W2, b2, out);
  } else {
    fused_kernel<false><<<NBLK, 64, 0, stream>>>(
        z, nullptr, nullptr, ei, ea, W1, b1, W2, b2, out);
  }
}

// Round 10
// 116.662 us; speedup vs baseline: 2.4830x; 1.0361x over previous
//
#include <hip/hip_runtime.h>

#define EDGES 1600000
#define NN    100000
#define ZD    64
#define FD    16
#define HID   128
#define BM    16          // edges per wave-tile
#define KP    160         // K padded (144 -> 160)
#define NBLK  6250        // 6250 blocks x 1 wave x 16 tiles x 16 edges = 1.6M
#define TPW   16

typedef __attribute__((ext_vector_type(8))) short bfrag;   // 8 bf16 = 4 VGPR
typedef __attribute__((ext_vector_type(4))) float f4v;     // 4 f32 acc

__device__ __forceinline__ unsigned short f2bf(float f) {
  unsigned u = __builtin_bit_cast(unsigned, f);
  u += 0x7fffu + ((u >> 16) & 1u);   // RNE
  return (unsigned short)(u >> 16);
}
__device__ __forceinline__ unsigned cvtpk(float lo, float hi) {
  unsigned r;
  asm("v_cvt_pk_bf16_f32 %0, %1, %2" : "=v"(r) : "v"(lo), "v"(hi));
  return r;
}

// z (f32) -> bf16 table in ws
__global__ void zconv_kernel(const float* __restrict__ z,
                             unsigned short* __restrict__ z16, int n4) {
  int i = blockIdx.x * blockDim.x + threadIdx.x;
  if (i >= n4) return;
  float4 f = reinterpret_cast<const float4*>(z)[i];
  ushort4 p;
  p.x = f2bf(f.x); p.y = f2bf(f.y); p.z = f2bf(f.z); p.w = f2bf(f.w);
  reinterpret_cast<ushort4*>(z16)[i] = p;
}

// W1 (f32, [144][128]) -> W1^T bf16 [128][160] (k-padded with zeros) in ws
__global__ void wtconv_kernel(const float* __restrict__ W1,
                              unsigned short* __restrict__ W16T) {
  int i = blockIdx.x * blockDim.x + threadIdx.x;
  if (i >= HID * KP) return;
  int h = i / KP, k = i % KP;
  W16T[i] = (k < 144) ? f2bf(W1[k * HID + h]) : (unsigned short)0;
}

template<bool ZB>
__global__ __launch_bounds__(64, 1) void fused_kernel(
    const float* __restrict__ zf, const unsigned short* __restrict__ z16,
    const unsigned short* __restrict__ W16T,
    const int* __restrict__ ei, const float* __restrict__ ea,
    const float* __restrict__ W1, const float* __restrict__ b1,
    const float* __restrict__ W2, const float* __restrict__ b2,
    float* __restrict__ out)
{
  const int lane = threadIdx.x & 63;
  const int e    = lane & 15;        // edge within tile (= A row = D col group)
  const int hi2  = lane >> 4;        // 0..3 (k-slice / D row-quad)
  const int T0   = blockIdx.x * TPW;

  // ---- W1^T fragments, W-stationary in registers (8 blk x 5 ks = 160 VGPR) ----
  // frag[j] = W1T[hid = blk*16+e][k = ks*32 + hi2*8 + j]
  bfrag Wb[8][5];
  if constexpr (ZB) {
    #pragma unroll
    for (int blk = 0; blk < 8; ++blk) {
      const unsigned short* wr = W16T + (size_t)(blk * 16 + e) * KP + hi2 * 8;
      #pragma unroll
      for (int ks = 0; ks < 5; ++ks)
        Wb[blk][ks] = *reinterpret_cast<const bfrag*>(wr + ks * 32);
    }
  } else {
    #pragma unroll
    for (int blk = 0; blk < 8; ++blk) {
      const int wcol = blk * 16 + e;
      #pragma unroll
      for (int ks = 0; ks < 5; ++ks) {
        bfrag f;
        #pragma unroll
        for (int j = 0; j < 8; ++j) {
          int kk = ks * 32 + hi2 * 8 + j;
          if (kk > 143) kk = 143;      // A-side zeroed there; just stay in-bounds
          f[j] = (short)f2bf(W1[kk * HID + wcol]);
        }
        Wb[blk][ks] = f;
      }
    }
  }

  float b1v[8], w2v[8];
  #pragma unroll
  for (int blk = 0; blk < 8; ++blk) {
    b1v[blk] = b1[blk * 16 + e];
    w2v[blk] = W2[blk * 16 + e];
  }
  const float bias2 = b2[0];

  // Memory clobber: after this point the compiler may NOT rematerialize the
  // Wb / b1v / w2v loads (memory could have changed) -> values must stay
  // register-resident for the whole kernel. This is the W-stationary pin.
  asm volatile("" ::: "memory");

  const unsigned eam = (hi2 < 2) ? 0xFFFFFFFFu : 0u;   // k>=144 pad mask
  const int eoff = (hi2 & 1) * 8;

  // gather of one tile's z fragments (per-lane: edge e, k-slice hi2)
#define GZ(x0, x1, x2, x3, si, di) do {                                        \
    if constexpr (ZB) {                                                        \
      const unsigned short* ps_ = z16 + (size_t)(si) * ZD + hi2 * 8;           \
      const unsigned short* pd_ = z16 + (size_t)(di) * ZD + hi2 * 8;           \
      x0 = *reinterpret_cast<const bfrag*>(ps_);                               \
      x1 = *reinterpret_cast<const bfrag*>(ps_ + 32);                          \
      x2 = *reinterpret_cast<const bfrag*>(pd_);                               \
      x3 = *reinterpret_cast<const bfrag*>(pd_ + 32);                          \
    } else {                                                                   \
      const float* ps_ = zf + (size_t)(si) * ZD + hi2 * 8;                     \
      const float* pd_ = zf + (size_t)(di) * ZD + hi2 * 8;                     \
      float4 a_, b_;                                                           \
      a_ = ((const float4*)ps_)[0]; b_ = ((const float4*)ps_)[1];              \
      { int4 q_ = {(int)cvtpk(a_.x,a_.y),(int)cvtpk(a_.z,a_.w),               \
                   (int)cvtpk(b_.x,b_.y),(int)cvtpk(b_.z,b_.w)};              \
        x0 = __builtin_bit_cast(bfrag, q_); }                                  \
      a_ = ((const float4*)(ps_+32))[0]; b_ = ((const float4*)(ps_+32))[1];    \
      { int4 q_ = {(int)cvtpk(a_.x,a_.y),(int)cvtpk(a_.z,a_.w),               \
                   (int)cvtpk(b_.x,b_.y),(int)cvtpk(b_.z,b_.w)};              \
        x1 = __builtin_bit_cast(bfrag, q_); }                                  \
      a_ = ((const float4*)pd_)[0]; b_ = ((const float4*)pd_)[1];              \
      { int4 q_ = {(int)cvtpk(a_.x,a_.y),(int)cvtpk(a_.z,a_.w),               \
                   (int)cvtpk(b_.x,b_.y),(int)cvtpk(b_.z,b_.w)};              \
        x2 = __builtin_bit_cast(bfrag, q_); }                                  \
      a_ = ((const float4*)(pd_+32))[0]; b_ = ((const float4*)(pd_+32))[1];    \
      { int4 q_ = {(int)cvtpk(a_.x,a_.y),(int)cvtpk(a_.z,a_.w),               \
                   (int)cvtpk(b_.x,b_.y),(int)cvtpk(b_.z,b_.w)};              \
        x3 = __builtin_bit_cast(bfrag, q_); }                                  \
    } } while (0)

  // ---- prologue: gather tile 0; ids for tile 1 ----
  int si0 = ei[(size_t)T0 * BM + e];
  int di0 = ei[(size_t)EDGES + (size_t)T0 * BM + e];
  bfrag c0, c1, c2, c3;
  GZ(c0, c1, c2, c3, si0, di0);
  const float* pe0 = ea + ((size_t)T0 * BM + e) * FD + eoff;
  float4 ca = ((const float4*)pe0)[0];
  float4 cb = ((const float4*)pe0)[1];
  int si1 = ei[(size_t)(T0 + 1) * BM + e];
  int di1 = ei[(size_t)EDGES + (size_t)(T0 + 1) * BM + e];

  for (int t = 0; t < TPW; ++t) {
    const int tt = T0 + t;

    // issue next-tile gathers (consumed next iteration -> latency hidden)
    bfrag n0, n1, n2, n3;
    GZ(n0, n1, n2, n3, si1, di1);
    const int te = (t + 1 < TPW) ? tt + 1 : tt;
    const float* pen = ea + ((size_t)te * BM + e) * FD + eoff;
    float4 na = ((const float4*)pen)[0];
    float4 nb = ((const float4*)pen)[1];
    // ids for tile t+2
    const int tf = (t + 2 < TPW) ? tt + 2 : T0 + TPW - 1;
    si1 = ei[(size_t)tf * BM + e];
    di1 = ei[(size_t)EDGES + (size_t)tf * BM + e];

    // build current ea fragment (k 128..159; upper 16 zero-padded)
    int4 q = {(int)(cvtpk(ca.x, ca.y) & eam), (int)(cvtpk(ca.z, ca.w) & eam),
              (int)(cvtpk(cb.x, cb.y) & eam), (int)(cvtpk(cb.z, cb.w) & eam)};
    bfrag c4 = __builtin_bit_cast(bfrag, q);

    // ---- 40 MFMAs: D[row=edge][col=hid], lane holds col=e, rows hi2*4+r ----
    float p0 = 0.f, p1 = 0.f, p2 = 0.f, p3 = 0.f;
    #pragma unroll
    for (int blk = 0; blk < 8; ++blk) {
      f4v acc = {0.f, 0.f, 0.f, 0.f};
      acc = __builtin_amdgcn_mfma_f32_16x16x32_bf16(c0, Wb[blk][0], acc, 0, 0, 0);
      acc = __builtin_amdgcn_mfma_f32_16x16x32_bf16(c1, Wb[blk][1], acc, 0, 0, 0);
      acc = __builtin_amdgcn_mfma_f32_16x16x32_bf16(c2, Wb[blk][2], acc, 0, 0, 0);
      acc = __builtin_amdgcn_mfma_f32_16x16x32_bf16(c3, Wb[blk][3], acc, 0, 0, 0);
      acc = __builtin_amdgcn_mfma_f32_16x16x32_bf16(c4, Wb[blk][4], acc, 0, 0, 0);
      p0 = fmaf(fmaxf(acc[0] + b1v[blk], 0.f), w2v[blk], p0);
      p1 = fmaf(fmaxf(acc[1] + b1v[blk], 0.f), w2v[blk], p1);
      p2 = fmaf(fmaxf(acc[2] + b1v[blk], 0.f), w2v[blk], p2);
      p3 = fmaf(fmaxf(acc[3] + b1v[blk], 0.f), w2v[blk], p3);
    }

    // reduce over the 16 hid-lanes of this group
    p0 += __shfl_xor(p0, 1); p0 += __shfl_xor(p0, 2);
    p0 += __shfl_xor(p0, 4); p0 += __shfl_xor(p0, 8);
    p1 += __shfl_xor(p1, 1); p1 += __shfl_xor(p1, 2);
    p1 += __shfl_xor(p1, 4); p1 += __shfl_xor(p1, 8);
    p2 += __shfl_xor(p2, 1); p2 += __shfl_xor(p2, 2);
    p2 += __shfl_xor(p2, 4); p2 += __shfl_xor(p2, 8);
    p3 += __shfl_xor(p3, 1); p3 += __shfl_xor(p3, 2);
    p3 += __shfl_xor(p3, 4); p3 += __shfl_xor(p3, 8);

    // lanes (e<4) store rows hi2*4 + (lane&3): 16 consecutive floats
    float v01 = (lane & 1) ? p1 : p0;
    float v23 = (lane & 1) ? p3 : p2;
    float v   = (lane & 2) ? v23 : v01;
    if (e < 4)
      out[(size_t)tt * BM + hi2 * 4 + (lane & 3)] =
          1.f / (1.f + __expf(-(v + bias2)));

    // rotate
    c0 = n0; c1 = n1; c2 = n2; c3 = n3; ca = na; cb = nb;
  }
#undef GZ
}

extern "C" void kernel_launch(void* const* d_in, const int* in_sizes, int n_in,
                              void* d_out, int out_size, void* d_ws, size_t ws_size,
                              hipStream_t stream) {
  const float* z  = (const float*)d_in[0];
  const int*   ei = (const int*)d_in[1];
  const float* ea = (const float*)d_in[2];
  const float* W1 = (const float*)d_in[3];
  const float* b1 = (const float*)d_in[4];
  const float* W2 = (const float*)d_in[5];
  const float* b2 = (const float*)d_in[6];
  float* out = (float*)d_out;

  const size_t z16_bytes = (size_t)NN * ZD * sizeof(unsigned short);
  const size_t wt_bytes  = (size_t)HID * KP * sizeof(unsigned short);
  if (ws_size >= z16_bytes + wt_bytes) {
    unsigned short* z16  = (unsigned short*)d_ws;
    unsigned short* W16T = z16 + (size_t)NN * ZD;
    const int n4 = NN * ZD / 4;
    zconv_kernel<<<(n4 + 255) / 256, 256, 0, stream>>>(z, z16, n4);
    wtconv_kernel<<<(HID * KP + 255) / 256, 256, 0, stream>>>(W1, W16T);
    fused_kernel<true><<<NBLK, 64, 0, stream>>>(
        z, z16, W16T, ei, ea, W1, b1, W2, b2, out);
  } else {
    fused_kernel<false><<<NBLK, 64, 0, stream>>>(
        z, nullptr, nullptr, ei, ea, W1, b1, W2, b2, out);
  }
}

// Round 11
// 99.309 us; speedup vs baseline: 2.9169x; 1.1747x over previous
//
#include <hip/hip_runtime.h>

#define EDGES 1600000
#define NN    100000
#define ZD    64
#define FD    16
#define HID   128
#define BM    32          // edges per wave-tile
#define THREADS 256
#define NBLK  1250        // 1250 blocks x 4 waves x 10 tiles x 32 edges = 1.6M
#define TPW   10
#define NFRAG 2560        // 4 blk x 10 ksteps x 64 lanes
#define WT_SHORTS (NFRAG * 8)

typedef __attribute__((ext_vector_type(8)))  short bfrag;   // 8 bf16 = 4 VGPR
typedef __attribute__((ext_vector_type(16))) float f16v;    // 16 f32 acc

__device__ __forceinline__ unsigned short f2bf(float f) {
  unsigned u = __builtin_bit_cast(unsigned, f);
  u += 0x7fffu + ((u >> 16) & 1u);   // RNE
  return (unsigned short)(u >> 16);
}
__device__ __forceinline__ unsigned cvtpk(float lo, float hi) {
  unsigned r;
  asm("v_cvt_pk_bf16_f32 %0, %1, %2" : "=v"(r) : "v"(lo), "v"(hi));
  return r;
}
__device__ __forceinline__ void gload16(const void* g, void* l) {
  __builtin_amdgcn_global_load_lds(
      (const __attribute__((address_space(1))) unsigned int*)g,
      (__attribute__((address_space(3))) unsigned int*)l, 16, 0, 0);
}

// z (f32) -> bf16 table in ws
__global__ void zconv_kernel(const float* __restrict__ z,
                             unsigned short* __restrict__ z16, int n4) {
  int i = blockIdx.x * blockDim.x + threadIdx.x;
  if (i >= n4) return;
  float4 f = reinterpret_cast<const float4*>(z)[i];
  ushort4 p;
  p.x = f2bf(f.x); p.y = f2bf(f.y); p.z = f2bf(f.z); p.w = f2bf(f.w);
  reinterpret_cast<ushort4*>(z16)[i] = p;
}

// Pre-swizzled MFMA A-fragment table for W1^T (+ b1 ones-column at k=144).
// frag index = (blk*10 + s)*64 + lane ; element j (0..7):
//   hid = blk*32 + (lane&31) ; k = s*16 + (lane>>5)*8 + j
//   val = k<144 ? W1[k][hid] : (k==144 ? b1[hid] : 0)
__global__ void wtab_kernel(const float* __restrict__ W1,
                            const float* __restrict__ b1,
                            unsigned short* __restrict__ WT) {
  int i = blockIdx.x * blockDim.x + threadIdx.x;
  if (i >= WT_SHORTS) return;
  int j    = i & 7;
  int frag = i >> 3;
  int lane = frag & 63;
  int s    = (frag >> 6) % 10;
  int blk  = frag / 640;
  int hid  = blk * 32 + (lane & 31);
  int k    = s * 16 + (lane >> 5) * 8 + j;
  float v = (k < 144) ? W1[k * HID + hid] : (k == 144 ? b1[hid] : 0.f);
  WT[i] = f2bf(v);
}

template<bool ZB>
__global__ __launch_bounds__(THREADS, 2) void fused_kernel(
    const float* __restrict__ zf, const unsigned short* __restrict__ z16,
    const unsigned short* __restrict__ WT,
    const int* __restrict__ ei, const float* __restrict__ ea,
    const float* __restrict__ W2, const float* __restrict__ b2,
    float* __restrict__ out)
{
  __shared__ __align__(16) int4 sW[NFRAG];   // 40 KiB

  const int tid  = threadIdx.x;
  const int lane = tid & 63;
  const int wid  = tid >> 6;
  const int e    = lane & 31;      // edge within tile (= MFMA B col = D col)
  const int hi   = lane >> 5;

  // ---- stage W-fragment table (lane-linear => gload_lds layout matches) ----
  #pragma unroll
  for (int c = 0; c < 10; ++c)
    gload16(WT + (size_t)(c * 256 + tid) * 8, &sW[c * 256 + tid]);
  asm volatile("s_waitcnt vmcnt(0)" ::: "memory");
  __syncthreads();                 // THE ONLY BARRIER

  // ---- per-lane W2 values: w2v[blk*16+rg] = W2[blk*32 + rh(rg,hi)] ----
  float w2v[64];
  #pragma unroll
  for (int blk = 0; blk < 4; ++blk)
    #pragma unroll
    for (int rg = 0; rg < 16; ++rg) {
      int rh = (rg & 3) + 8 * (rg >> 2) + 4 * hi;
      w2v[blk * 16 + rg] = W2[blk * 32 + rh];
    }
  const float bias2 = b2[0];

  // ones+b1 column fragment (k=144 -> 1.0, k>144 -> 0)
  int4 oq = {0, 0, 0, 0};
  if (hi == 0) oq.x = 0x3F80;      // bf16 1.0 in element j=0
  const bfrag cone = __builtin_bit_cast(bfrag, oq);

  // gather one tile's 9 edge B-fragments into named registers
#define GZ(x0, x1, x2, x3, x4, x5, x6, x7, x8, si, di, tt) do {                \
    if constexpr (ZB) {                                                        \
      const unsigned short* ps_ = z16 + (size_t)(si) * ZD + hi * 8;            \
      const unsigned short* pd_ = z16 + (size_t)(di) * ZD + hi * 8;            \
      x0 = *reinterpret_cast<const bfrag*>(ps_);                               \
      x1 = *reinterpret_cast<const bfrag*>(ps_ + 16);                          \
      x2 = *reinterpret_cast<const bfrag*>(ps_ + 32);                          \
      x3 = *reinterpret_cast<const bfrag*>(ps_ + 48);                          \
      x4 = *reinterpret_cast<const bfrag*>(pd_);                               \
      x5 = *reinterpret_cast<const bfrag*>(pd_ + 16);                          \
      x6 = *reinterpret_cast<const bfrag*>(pd_ + 32);                          \
      x7 = *reinterpret_cast<const bfrag*>(pd_ + 48);                          \
    } else {                                                                   \
      const float* ps_ = zf + (size_t)(si) * ZD + hi * 8;                      \
      const float* pd_ = zf + (size_t)(di) * ZD + hi * 8;                      \
      float4 a_, b_;                                                           \
      a_ = ((const float4*)ps_)[0]; b_ = ((const float4*)ps_)[1];              \
      { int4 q_ = {(int)cvtpk(a_.x,a_.y),(int)cvtpk(a_.z,a_.w),                \
                   (int)cvtpk(b_.x,b_.y),(int)cvtpk(b_.z,b_.w)};               \
        x0 = __builtin_bit_cast(bfrag, q_); }                                  \
      a_ = ((const float4*)(ps_+16))[0]; b_ = ((const float4*)(ps_+16))[1];    \
      { int4 q_ = {(int)cvtpk(a_.x,a_.y),(int)cvtpk(a_.z,a_.w),                \
                   (int)cvtpk(b_.x,b_.y),(int)cvtpk(b_.z,b_.w)};               \
        x1 = __builtin_bit_cast(bfrag, q_); }                                  \
      a_ = ((const float4*)(ps_+32))[0]; b_ = ((const float4*)(ps_+32))[1];    \
      { int4 q_ = {(int)cvtpk(a_.x,a_.y),(int)cvtpk(a_.z,a_.w),                \
                   (int)cvtpk(b_.x,b_.y),(int)cvtpk(b_.z,b_.w)};               \
        x2 = __builtin_bit_cast(bfrag, q_); }                                  \
      a_ = ((const float4*)(ps_+48))[0]; b_ = ((const float4*)(ps_+48))[1];    \
      { int4 q_ = {(int)cvtpk(a_.x,a_.y),(int)cvtpk(a_.z,a_.w),                \
                   (int)cvtpk(b_.x,b_.y),(int)cvtpk(b_.z,b_.w)};               \
        x3 = __builtin_bit_cast(bfrag, q_); }                                  \
      a_ = ((const float4*)pd_)[0]; b_ = ((const float4*)pd_)[1];              \
      { int4 q_ = {(int)cvtpk(a_.x,a_.y),(int)cvtpk(a_.z,a_.w),                \
                   (int)cvtpk(b_.x,b_.y),(int)cvtpk(b_.z,b_.w)};               \
        x4 = __builtin_bit_cast(bfrag, q_); }                                  \
      a_ = ((const float4*)(pd_+16))[0]; b_ = ((const float4*)(pd_+16))[1];    \
      { int4 q_ = {(int)cvtpk(a_.x,a_.y),(int)cvtpk(a_.z,a_.w),                \
                   (int)cvtpk(b_.x,b_.y),(int)cvtpk(b_.z,b_.w)};               \
        x5 = __builtin_bit_cast(bfrag, q_); }                                  \
      a_ = ((const float4*)(pd_+32))[0]; b_ = ((const float4*)(pd_+32))[1];    \
      { int4 q_ = {(int)cvtpk(a_.x,a_.y),(int)cvtpk(a_.z,a_.w),                \
                   (int)cvtpk(b_.x,b_.y),(int)cvtpk(b_.z,b_.w)};               \
        x6 = __builtin_bit_cast(bfrag, q_); }                                  \
      a_ = ((const float4*)(pd_+48))[0]; b_ = ((const float4*)(pd_+48))[1];    \
      { int4 q_ = {(int)cvtpk(a_.x,a_.y),(int)cvtpk(a_.z,a_.w),                \
                   (int)cvtpk(b_.x,b_.y),(int)cvtpk(b_.z,b_.w)};               \
        x7 = __builtin_bit_cast(bfrag, q_); }                                  \
    }                                                                          \
    const float* pe_ = ea + ((size_t)(tt) * BM + e) * FD + hi * 8;             \
    float4 ea_ = ((const float4*)pe_)[0];                                      \
    float4 eb_ = ((const float4*)pe_)[1];                                      \
    { int4 q_ = {(int)cvtpk(ea_.x,ea_.y),(int)cvtpk(ea_.z,ea_.w),              \
                 (int)cvtpk(eb_.x,eb_.y),(int)cvtpk(eb_.z,eb_.w)};             \
      x8 = __builtin_bit_cast(bfrag, q_); }                                    \
  } while (0)

  // ---- wave-autonomous tile loop ----
  const int gw = blockIdx.x * 4 + wid;   // global wave id
  const int T0 = gw * TPW;

  int si = ei[(size_t)T0 * BM + e];
  int di = ei[(size_t)EDGES + (size_t)T0 * BM + e];
  bfrag c0, c1, c2, c3, c4, c5, c6, c7, c8;
  GZ(c0, c1, c2, c3, c4, c5, c6, c7, c8, si, di, T0);
  int s1 = ei[(size_t)(T0 + 1) * BM + e];
  int d1 = ei[(size_t)EDGES + (size_t)(T0 + 1) * BM + e];

  for (int t = 0; t < TPW; ++t) {
    const int tt = T0 + t;

    // issue next tile's gathers (consumed next iteration)
    const int tn = (t + 1 < TPW) ? tt + 1 : tt;
    bfrag n0, n1, n2, n3, n4, n5, n6, n7, n8;
    GZ(n0, n1, n2, n3, n4, n5, n6, n7, n8, s1, d1, tn);

    // ids 2 tiles ahead
    const int tf = (t + 2 < TPW) ? tt + 2 : T0 + TPW - 1;
    s1 = ei[(size_t)tf * BM + e];
    d1 = ei[(size_t)EDGES + (size_t)tf * BM + e];

    // ---- 4 hid-blocks x 10 MFMAs; W frags re-read from LDS each tile ----
    float p = 0.f;
    #pragma unroll
    for (int blk = 0; blk < 4; ++blk) {
      const int4* wp = &sW[blk * 640 + lane];
      bfrag w0 = *reinterpret_cast<const bfrag*>(wp + 0 * 64);
      bfrag w1 = *reinterpret_cast<const bfrag*>(wp + 1 * 64);
      bfrag w2 = *reinterpret_cast<const bfrag*>(wp + 2 * 64);
      bfrag w3 = *reinterpret_cast<const bfrag*>(wp + 3 * 64);
      bfrag w4 = *reinterpret_cast<const bfrag*>(wp + 4 * 64);
      bfrag w5 = *reinterpret_cast<const bfrag*>(wp + 5 * 64);
      bfrag w6 = *reinterpret_cast<const bfrag*>(wp + 6 * 64);
      bfrag w7 = *reinterpret_cast<const bfrag*>(wp + 7 * 64);
      bfrag w8 = *reinterpret_cast<const bfrag*>(wp + 8 * 64);
      bfrag w9 = *reinterpret_cast<const bfrag*>(wp + 9 * 64);

      f16v acc;
      #pragma unroll
      for (int rg = 0; rg < 16; ++rg) acc[rg] = 0.f;
      acc = __builtin_amdgcn_mfma_f32_32x32x16_bf16(w0, c0, acc, 0, 0, 0);
      acc = __builtin_amdgcn_mfma_f32_32x32x16_bf16(w1, c1, acc, 0, 0, 0);
      acc = __builtin_amdgcn_mfma_f32_32x32x16_bf16(w2, c2, acc, 0, 0, 0);
      acc = __builtin_amdgcn_mfma_f32_32x32x16_bf16(w3, c3, acc, 0, 0, 0);
      acc = __builtin_amdgcn_mfma_f32_32x32x16_bf16(w4, c4, acc, 0, 0, 0);
      acc = __builtin_amdgcn_mfma_f32_32x32x16_bf16(w5, c5, acc, 0, 0, 0);
      acc = __builtin_amdgcn_mfma_f32_32x32x16_bf16(w6, c6, acc, 0, 0, 0);
      acc = __builtin_amdgcn_mfma_f32_32x32x16_bf16(w7, c7, acc, 0, 0, 0);
      acc = __builtin_amdgcn_mfma_f32_32x32x16_bf16(w8, c8, acc, 0, 0, 0);
      acc = __builtin_amdgcn_mfma_f32_32x32x16_bf16(w9, cone, acc, 0, 0, 0);

      // ReLU + W2 dot (b1 already inside acc via ones-column)
      #pragma unroll
      for (int rg = 0; rg < 16; ++rg)
        p = fmaf(fmaxf(acc[rg], 0.f), w2v[blk * 16 + rg], p);
    }

    p += __shfl_xor(p, 32);      // combine hi-half rows
    if (lane < 32)
      out[(size_t)tt * BM + lane] = 1.f / (1.f + __expf(-(p + bias2)));

    // rotate prefetched fragments
    c0 = n0; c1 = n1; c2 = n2; c3 = n3; c4 = n4;
    c5 = n5; c6 = n6; c7 = n7; c8 = n8;
  }
#undef GZ
}

extern "C" void kernel_launch(void* const* d_in, const int* in_sizes, int n_in,
                              void* d_out, int out_size, void* d_ws, size_t ws_size,
                              hipStream_t stream) {
  const float* z  = (const float*)d_in[0];
  const int*   ei = (const int*)d_in[1];
  const float* ea = (const float*)d_in[2];
  const float* W1 = (const float*)d_in[3];
  const float* b1 = (const float*)d_in[4];
  const float* W2 = (const float*)d_in[5];
  const float* b2 = (const float*)d_in[6];
  float* out = (float*)d_out;

  const size_t z16_bytes = (size_t)NN * ZD * sizeof(unsigned short);
  const size_t wt_bytes  = (size_t)WT_SHORTS * sizeof(unsigned short);

  if (ws_size >= z16_bytes + wt_bytes) {
    unsigned short* z16 = (unsigned short*)d_ws;
    unsigned short* WT  = z16 + (size_t)NN * ZD;
    const int n4 = NN * ZD / 4;
    zconv_kernel<<<(n4 + 255) / 256, 256, 0, stream>>>(z, z16, n4);
    wtab_kernel<<<(WT_SHORTS + 255) / 256, 256, 0, stream>>>(W1, b1, WT);
    fused_kernel<true><<<NBLK, THREADS, 0, stream>>>(
        z, z16, WT, ei, ea, W2, b2, out);
  } else {
    // ws too small for z16 table: keep f32 z gathers, WT at ws base
    unsigned short* WT = (unsigned short*)d_ws;
    wtab_kernel<<<(WT_SHORTS + 255) / 256, 256, 0, stream>>>(W1, b1, WT);
    fused_kernel<false><<<NBLK, THREADS, 0, stream>>>(
        z, nullptr, WT, ei, ea, W2, b2, out);
  }
}